// Round 22
// baseline (696.608 us; speedup 1.0000x reference)
//
#include <hip/hip_runtime.h>

#define T_STEPS 1000
#define BATCH   256
#define NHID    200
#define ROWF    200        // floats per LDS row (800 B, 16B-aligned)
#define NROWS   196        // source rows in LDS; rows 196-199 in registers (wave 7)
#define BETA_C  0.85f
#define THR_C   1.0f

// WT2 row i (source neuron i, i<196) holds at float offset lo*4+k (lo<50,k<4):
// Wrec[(lo+50k)][i]. Lane lo reads ONE ds_read_b128 per firing source,
// yielding weights for outputs {lo, lo+50, lo+100, lo+150}.
//
// 8 waves per batch element. Wave pair (w, w+4) gathers word w's low/high
// 25-bit half (~3.75 firing -> 1-2 trips). Partials go to
// part[hi][comp][src][lane] with plain stores (no atomics). After BAR1 BOTH
// waves of a pair redundantly read all 8 partials, reduce in fixed order
// (((p0l+p0h)+(p1l+p1h))+(p2l+p2h))+(p3l+p3h) — the order R14 validated —
// update word w's neurons, and ballot: both waves derive the identical
// full-word mask locally, so there is NO mask exchange and NO role
// divergence (hi wave only skips the spike store). Sources 196-199 (hi-half
// bits 21-24 of word 3) live in registers on wave 7, added ascending after
// the LDS bits. Two lgkm-only barriers/step (R19-validated discipline);
// inputs batched 8 steps/group (SMEM shares lgkmcnt). cur2 via 2nd kernel.

#define BARRIER_LGKM \
    asm volatile("s_waitcnt lgkmcnt(0)\n\ts_barrier" ::: "memory");

__launch_bounds__(512, 1)
__global__ void rsnn_kernel(const float* __restrict__ X,
                            const float* __restrict__ W1,
                            const float* __restrict__ b1,
                            const float* __restrict__ Wrec,
                            const float* __restrict__ brec,
                            float* __restrict__ out_spk) {
#pragma clang fp contract(off)
    __shared__ float WT2[NROWS * ROWF];    // 156,800 B (source rows 0..195)
    __shared__ float part[2][4][4][50];    //   6,400 B [hi][comp][src][lane]

    const int tid = threadIdx.x;
    const int l   = tid & 63;            // lane
    const int wv  = tid >> 6;            // wave 0..7
    const int w   = wv & 3;              // source & output word id
    const int hi  = wv >> 2;             // 0 = low 25 bits, 1 = high 25 bits
    const int b   = blockIdx.x;

    // ---- stage Wrec rows 0..195 (permuted transpose) into LDS ----
    for (int idx = tid; idx < NHID * NHID; idx += 512) {
        int r = idx / NHID;              // Wrec row  (output neuron)
        int i = idx - r * NHID;          // Wrec col  (source neuron)
        if (i < NROWS) {
            int lo = r % 50, k = r / 50;
            WT2[i * ROWF + lo * 4 + k] = Wrec[idx];
        }
    }
    __syncthreads();

    const int lc = (l < 50) ? l : 49;    // lanes 50-63 duplicate lane 49
    const int oc = 50 * w + lc;          // this lane's output neuron
    const float w10 = W1[oc * 3 + 0], w11 = W1[oc * 3 + 1], w12 = W1[oc * 3 + 2];
    const float b1j = b1[oc], brj = brec[oc];

    // register rows: sources 196..199 (consumed by wave 7 only)
    float4 rr[4];
#pragma unroll
    for (int j = 0; j < 4; ++j) {
        rr[j].x = Wrec[(lc +   0) * NHID + NROWS + j];
        rr[j].y = Wrec[(lc +  50) * NHID + NROWS + j];
        rr[j].z = Wrec[(lc + 100) * NHID + NROWS + j];
        rr[j].w = Wrec[(lc + 150) * NHID + NROWS + j];
    }

    float mem = 0.f;
    unsigned long long bm = 0;           // own word's full spike mask

    const float* xp = X + (size_t)b * 3;

    const float* ldsrow  = WT2 + (size_t)lc * 4;
    const int    gbase   = 50 * w + 25 * hi;   // first source of my half
    const bool   w7      = (wv == 7);
    float*       spk_out = out_spk + (size_t)b * NHID + 50 * w + lc;

    // ---- current 8-step group of inputs, fully in registers ----
    float xc[8][3];
#pragma unroll
    for (int k = 0; k < 8; ++k) {
        xc[k][0] = xp[(size_t)k * (BATCH * 3) + 0];
        xc[k][1] = xp[(size_t)k * (BATCH * 3) + 1];
        xc[k][2] = xp[(size_t)k * (BATCH * 3) + 2];
    }

#define REC_WORD(MASK, BASE)                                                          \
    {                                                                                 \
        unsigned long long m = (MASK);                                                \
        while (m) {                                                                   \
            int i0 = __builtin_ctzll(m); m &= m - 1;                                  \
            bool h1 = m != 0; int i1 = h1 ? __builtin_ctzll(m) : i0; if (h1) m &= m - 1; \
            bool h2 = m != 0; int i2 = h2 ? __builtin_ctzll(m) : i0; if (h2) m &= m - 1; \
            bool h3 = m != 0; int i3 = h3 ? __builtin_ctzll(m) : i0; if (h3) m &= m - 1; \
            const float4 v0 = *(const float4*)(ldsrow + (i0 + (BASE)) * ROWF);        \
            const float4 v1 = *(const float4*)(ldsrow + (i1 + (BASE)) * ROWF);        \
            const float4 v2 = *(const float4*)(ldsrow + (i2 + (BASE)) * ROWF);        \
            const float4 v3 = *(const float4*)(ldsrow + (i3 + (BASE)) * ROWF);        \
            pr0 += v0.x; pr1 += v0.y; pr2 += v0.z; pr3 += v0.w;                       \
            if (h1) { pr0 += v1.x; pr1 += v1.y; pr2 += v1.z; pr3 += v1.w; }           \
            if (h2) { pr0 += v2.x; pr1 += v2.y; pr2 += v2.z; pr3 += v2.w; }           \
            if (h3) { pr0 += v3.x; pr1 += v3.y; pr2 += v3.z; pr3 += v3.w; }           \
        }                                                                             \
    }

// One time step (two barriers; both waves of a pair do identical update).
#define STEP(T, K)                                                       \
    {                                                                    \
        const int t = (T);                                               \
                                                                         \
        float pr0 = 0.f, pr1 = 0.f, pr2 = 0.f, pr3 = 0.f;                \
        unsigned long long mh = hi ? (bm >> 25) : (bm & 0x1FFFFFFull);   \
        if (w7) {   /* sources 175..195 from LDS, 196..199 from regs */  \
            unsigned long long ml = mh & ((1ull << 21) - 1);             \
            REC_WORD(ml, gbase)                                          \
            if (mh & (1ull << 21)) { pr0 += rr[0].x; pr1 += rr[0].y;     \
                                     pr2 += rr[0].z; pr3 += rr[0].w; }   \
            if (mh & (1ull << 22)) { pr0 += rr[1].x; pr1 += rr[1].y;     \
                                     pr2 += rr[1].z; pr3 += rr[1].w; }   \
            if (mh & (1ull << 23)) { pr0 += rr[2].x; pr1 += rr[2].y;     \
                                     pr2 += rr[2].z; pr3 += rr[2].w; }   \
            if (mh & (1ull << 24)) { pr0 += rr[3].x; pr1 += rr[3].y;     \
                                     pr2 += rr[3].z; pr3 += rr[3].w; }   \
        } else {                                                         \
            REC_WORD(mh, gbase)                                          \
        }                                                                \
                                                                         \
        if (l < 50) {                                                    \
            part[hi][0][w][l] = pr0;                                     \
            part[hi][1][w][l] = pr1;                                     \
            part[hi][2][w][l] = pr2;                                     \
            part[hi][3][w][l] = pr3;                                     \
        }                                                                \
        BARRIER_LGKM                                                     \
                                                                         \
        float p0l = part[0][w][0][lc], p0h = part[1][w][0][lc];          \
        float p1l = part[0][w][1][lc], p1h = part[1][w][1][lc];          \
        float p2l = part[0][w][2][lc], p2h = part[1][w][2][lc];          \
        float p3l = part[0][w][3][lc], p3h = part[1][w][3][lc];          \
        float rec = (((p0l + p0h) + (p1l + p1h))                         \
                     + (p2l + p2h)) + (p3l + p3h);                       \
        BARRIER_LGKM                                                     \
                                                                         \
        float c1 = fmaf(xc[K][2], w12,                                   \
                        fmaf(xc[K][1], w11, xc[K][0] * w10)) + b1j;      \
        float ba = ((BETA_C * mem + c1) + rec) + brj;                    \
        float nm = (mem > THR_C) ? 0.f : ba;                             \
        float sp = (nm > THR_C) ? 1.f : 0.f;                             \
        mem = nm;                                                        \
                                                                         \
        if (hi == 0 && l < 50)                                           \
            spk_out[(size_t)t * BATCH * NHID] = sp;                      \
        bm = __ballot((l < 50) && (sp > 0.5f));                          \
    }

    for (int g = 0; g < T_STEPS; g += 8) {
        // issue next group's 24 input loads; SMEM latency drained once
        const int gn = (g + 8 < T_STEPS) ? g + 8 : 0;   // last group: dummy
        float xn[8][3];
#pragma unroll
        for (int k = 0; k < 8; ++k) {
            xn[k][0] = xp[(size_t)(gn + k) * (BATCH * 3) + 0];
            xn[k][1] = xp[(size_t)(gn + k) * (BATCH * 3) + 1];
            xn[k][2] = xp[(size_t)(gn + k) * (BATCH * 3) + 2];
        }

        STEP(g + 0, 0)
        STEP(g + 1, 1)
        STEP(g + 2, 2)
        STEP(g + 3, 3)
        STEP(g + 4, 4)
        STEP(g + 5, 5)
        STEP(g + 6, 6)
        STEP(g + 7, 7)

#pragma unroll
        for (int k = 0; k < 8; ++k) {
            xc[k][0] = xn[k][0];
            xc[k][1] = xn[k][1];
            xc[k][2] = xn[k][2];
        }
    }
#undef STEP
#undef REC_WORD
}

// cur2[t,b] = sum_j spk[t,b,j]*W2[j] + b2 — recomputed from stored spikes
// (L3-resident). Terminal output: tree reduction order is safe.
__launch_bounds__(256)
__global__ void cur2_kernel(const float* __restrict__ spk,
                            const float* __restrict__ W2,
                            const float* __restrict__ b2,
                            float* __restrict__ out) {
    const int lane = threadIdx.x & 63;
    const int wid  = (int)((blockIdx.x * blockDim.x + threadIdx.x) >> 6);
    const int nw   = (int)((gridDim.x * blockDim.x) >> 6);

    float4 w2v = {0.f, 0.f, 0.f, 0.f};
    if (lane < 50) w2v = *(const float4*)(W2 + lane * 4);
    const float b2v = b2[0];

    for (int p = wid; p < T_STEPS * BATCH; p += nw) {
        float4 sv = {0.f, 0.f, 0.f, 0.f};
        if (lane < 50) sv = *(const float4*)(spk + (size_t)p * NHID + lane * 4);
        float a = fmaf(sv.w, w2v.w, fmaf(sv.z, w2v.z,
                  fmaf(sv.y, w2v.y, sv.x * w2v.x)));
#pragma unroll
        for (int o = 32; o >= 1; o >>= 1) a += __shfl_xor(a, o);
        if (lane == 0) out[p] = a + b2v;   // p = t*BATCH + b
    }
}

extern "C" void kernel_launch(void* const* d_in, const int* in_sizes, int n_in,
                              void* d_out, int out_size, void* d_ws, size_t ws_size,
                              hipStream_t stream) {
    const float* X    = (const float*)d_in[0];
    const float* W1   = (const float*)d_in[1];
    const float* b1   = (const float*)d_in[2];
    const float* Wrec = (const float*)d_in[3];
    const float* brec = (const float*)d_in[4];
    const float* W2   = (const float*)d_in[5];
    const float* b2   = (const float*)d_in[6];

    float* out_cur2 = (float*)d_out;                            // [T,B,1] flat
    float* out_spk  = (float*)d_out + (size_t)T_STEPS * BATCH;  // [T,B,200] flat

    rsnn_kernel<<<BATCH, 512, 0, stream>>>(X, W1, b1, Wrec, brec, out_spk);
    cur2_kernel<<<1024, 256, 0, stream>>>(out_spk, W2, b2, out_cur2);
}

// Round 23
// 553.601 us; speedup vs baseline: 1.2583x; 1.2583x over previous
//
#include <hip/hip_runtime.h>

#define T_STEPS 1000
#define BATCH   256
#define NHID    200
#define ROWF    200        // floats per LDS row (800 B, 16B-aligned)
#define BETA_C  0.85f
#define THR_C   1.0f

// LDS holds 49 source rows per word (sources 50w..50w+48 at LDS row 49w+i).
// Row layout: float offset lo*4+k (lo<50,k<4) = Wrec[(lo+50k)][source].
// Source 50w+49 (bit 49 of word w) lives in ONE float4 of registers per
// lane of wave w — every wave pays the same tiny uniform branch (this is
// R21's LDS-freeing trick, balanced across waves instead of loading wave 3).
//
// 4 waves per batch element; wave w gathers source word w (4-wide b128
// trips, ascending) and owns output word w. Partial exchange is TRUE
// double-buffered (part[t&1]) -> ONE lgkm-only barrier per step, provably
// race-free: write_{t+2}[P] begins only after BAR_{t+1}, which each wave
// signals only after its lgkmcnt(0)-drained read_t[P]; WAW pairs are two
// barriers apart. (Same scheme as R21, validated under graph replay.)
// Inputs batched 8 steps/group into registers (SMEM shares lgkmcnt; the
// ~200-cyc scalar-load drain is paid once per 8 steps, not every step).
// cur2 recomputed by a second kernel from stored spikes.

#define BARRIER_LGKM \
    asm volatile("s_waitcnt lgkmcnt(0)\n\ts_barrier" ::: "memory");

__launch_bounds__(256, 1)
__global__ void rsnn_kernel(const float* __restrict__ X,
                            const float* __restrict__ W1,
                            const float* __restrict__ b1,
                            const float* __restrict__ Wrec,
                            const float* __restrict__ brec,
                            float* __restrict__ out_spk) {
#pragma clang fp contract(off)
    __shared__ float WT2[196 * ROWF];      // 156,800 B (49 rows x 4 words)
    __shared__ float part[2][4][4][50];    //   6,400 B [parity][comp][src][lane]

    const int tid = threadIdx.x;
    const int l   = tid & 63;            // lane
    const int w   = tid >> 6;            // wave id = source & output word id
    const int b   = blockIdx.x;

    // ---- stage Wrec (permuted transpose) into LDS, skipping bit-49 rows ----
    for (int idx = tid; idx < NHID * NHID; idx += 256) {
        int r  = idx / NHID;             // Wrec row  (output neuron)
        int i  = idx - r * NHID;         // Wrec col  (source neuron)
        int iw = i / 50, ib = i - iw * 50;
        if (ib < 49) {
            int lo = r % 50, k = r / 50;
            WT2[(49 * iw + ib) * ROWF + lo * 4 + k] = Wrec[idx];
        }
    }
    __syncthreads();

    const int lc = (l < 50) ? l : 49;    // lanes 50-63 duplicate lane 49
    const int oc = 50 * w + lc;          // this lane's output neuron
    const float w10 = W1[oc * 3 + 0], w11 = W1[oc * 3 + 1], w12 = W1[oc * 3 + 2];
    const float b1j = b1[oc], brj = brec[oc];

    // register row: own word's source 50w+49 (bit 49), 4 output components
    float4 r49;
    {
        const int s49 = 50 * w + 49;
        r49.x = Wrec[(lc +   0) * NHID + s49];
        r49.y = Wrec[(lc +  50) * NHID + s49];
        r49.z = Wrec[(lc + 100) * NHID + s49];
        r49.w = Wrec[(lc + 150) * NHID + s49];
    }

    float mem = 0.f;
    unsigned long long bm = 0;           // own word's spike mask

    const float* xp = X + (size_t)b * 3;

    const float* ldsrow  = WT2 + (size_t)lc * 4;
    const int    gbase   = 49 * w;       // LDS row base of my word
    float*       spk_out = out_spk + (size_t)b * NHID + 50 * w + lc;

    // ---- current 8-step group of inputs, fully in registers ----
    float xc[8][3];
#pragma unroll
    for (int k = 0; k < 8; ++k) {
        xc[k][0] = xp[(size_t)k * (BATCH * 3) + 0];
        xc[k][1] = xp[(size_t)k * (BATCH * 3) + 1];
        xc[k][2] = xp[(size_t)k * (BATCH * 3) + 2];
    }

#define REC_WORD(MASK, BASE)                                                          \
    {                                                                                 \
        unsigned long long m = (MASK);                                                \
        while (m) {                                                                   \
            int i0 = __builtin_ctzll(m); m &= m - 1;                                  \
            bool h1 = m != 0; int i1 = h1 ? __builtin_ctzll(m) : i0; if (h1) m &= m - 1; \
            bool h2 = m != 0; int i2 = h2 ? __builtin_ctzll(m) : i0; if (h2) m &= m - 1; \
            bool h3 = m != 0; int i3 = h3 ? __builtin_ctzll(m) : i0; if (h3) m &= m - 1; \
            const float4 v0 = *(const float4*)(ldsrow + (i0 + (BASE)) * ROWF);        \
            const float4 v1 = *(const float4*)(ldsrow + (i1 + (BASE)) * ROWF);        \
            const float4 v2 = *(const float4*)(ldsrow + (i2 + (BASE)) * ROWF);        \
            const float4 v3 = *(const float4*)(ldsrow + (i3 + (BASE)) * ROWF);        \
            pr0 += v0.x; pr1 += v0.y; pr2 += v0.z; pr3 += v0.w;                       \
            if (h1) { pr0 += v1.x; pr1 += v1.y; pr2 += v1.z; pr3 += v1.w; }           \
            if (h2) { pr0 += v2.x; pr1 += v2.y; pr2 += v2.z; pr3 += v2.w; }           \
            if (h3) { pr0 += v3.x; pr1 += v3.y; pr2 += v3.z; pr3 += v3.w; }           \
        }                                                                             \
    }

// One time step; P = parity buffer (t & 1). ONE barrier per step.
// Bit 49 added AFTER bits 0-48 (ascending order preserved; plain add).
#define STEP(T, K, P)                                                    \
    {                                                                    \
        const int t = (T);                                               \
                                                                         \
        float pr0 = 0.f, pr1 = 0.f, pr2 = 0.f, pr3 = 0.f;                \
        unsigned long long mlo = bm & ((1ull << 49) - 1);                \
        REC_WORD(mlo, gbase)                                             \
        if (bm & (1ull << 49)) {                                         \
            pr0 += r49.x; pr1 += r49.y; pr2 += r49.z; pr3 += r49.w;      \
        }                                                                \
                                                                         \
        if (l < 50) {                                                    \
            part[P][0][w][l] = pr0;                                      \
            part[P][1][w][l] = pr1;                                      \
            part[P][2][w][l] = pr2;                                      \
            part[P][3][w][l] = pr3;                                      \
        }                                                                \
        BARRIER_LGKM                                                     \
                                                                         \
        float p0 = part[P][w][0][lc], p1 = part[P][w][1][lc];            \
        float p2 = part[P][w][2][lc], p3 = part[P][w][3][lc];            \
        float rec = ((p0 + p1) + p2) + p3;                               \
                                                                         \
        float c1 = fmaf(xc[K][2], w12,                                   \
                        fmaf(xc[K][1], w11, xc[K][0] * w10)) + b1j;      \
        float ba = ((BETA_C * mem + c1) + rec) + brj;                    \
        float nm = (mem > THR_C) ? 0.f : ba;                             \
        float sp = (nm > THR_C) ? 1.f : 0.f;                             \
        mem = nm;                                                        \
                                                                         \
        if (l < 50)                                                      \
            spk_out[(size_t)t * BATCH * NHID] = sp;                      \
        bm = __ballot((l < 50) && (sp > 0.5f));                          \
    }

    for (int g = 0; g < T_STEPS; g += 8) {
        // issue next group's 24 input loads; their SMEM latency is drained
        // once (first barrier of step g), steps g+1..g+7 are SMEM-free
        const int gn = (g + 8 < T_STEPS) ? g + 8 : 0;   // last group: dummy
        float xn[8][3];
#pragma unroll
        for (int k = 0; k < 8; ++k) {
            xn[k][0] = xp[(size_t)(gn + k) * (BATCH * 3) + 0];
            xn[k][1] = xp[(size_t)(gn + k) * (BATCH * 3) + 1];
            xn[k][2] = xp[(size_t)(gn + k) * (BATCH * 3) + 2];
        }

        STEP(g + 0, 0, 0)
        STEP(g + 1, 1, 1)
        STEP(g + 2, 2, 0)
        STEP(g + 3, 3, 1)
        STEP(g + 4, 4, 0)
        STEP(g + 5, 5, 1)
        STEP(g + 6, 6, 0)
        STEP(g + 7, 7, 1)

#pragma unroll
        for (int k = 0; k < 8; ++k) {
            xc[k][0] = xn[k][0];
            xc[k][1] = xn[k][1];
            xc[k][2] = xn[k][2];
        }
    }
#undef STEP
#undef REC_WORD
}

// cur2[t,b] = sum_j spk[t,b,j]*W2[j] + b2 — recomputed from stored spikes
// (L3-resident). Terminal output: tree reduction order is safe.
__launch_bounds__(256)
__global__ void cur2_kernel(const float* __restrict__ spk,
                            const float* __restrict__ W2,
                            const float* __restrict__ b2,
                            float* __restrict__ out) {
    const int lane = threadIdx.x & 63;
    const int wid  = (int)((blockIdx.x * blockDim.x + threadIdx.x) >> 6);
    const int nw   = (int)((gridDim.x * blockDim.x) >> 6);

    float4 w2v = {0.f, 0.f, 0.f, 0.f};
    if (lane < 50) w2v = *(const float4*)(W2 + lane * 4);
    const float b2v = b2[0];

    for (int p = wid; p < T_STEPS * BATCH; p += nw) {
        float4 sv = {0.f, 0.f, 0.f, 0.f};
        if (lane < 50) sv = *(const float4*)(spk + (size_t)p * NHID + lane * 4);
        float a = fmaf(sv.w, w2v.w, fmaf(sv.z, w2v.z,
                  fmaf(sv.y, w2v.y, sv.x * w2v.x)));
#pragma unroll
        for (int o = 32; o >= 1; o >>= 1) a += __shfl_xor(a, o);
        if (lane == 0) out[p] = a + b2v;   // p = t*BATCH + b
    }
}

extern "C" void kernel_launch(void* const* d_in, const int* in_sizes, int n_in,
                              void* d_out, int out_size, void* d_ws, size_t ws_size,
                              hipStream_t stream) {
    const float* X    = (const float*)d_in[0];
    const float* W1   = (const float*)d_in[1];
    const float* b1   = (const float*)d_in[2];
    const float* Wrec = (const float*)d_in[3];
    const float* brec = (const float*)d_in[4];
    const float* W2   = (const float*)d_in[5];
    const float* b2   = (const float*)d_in[6];

    float* out_cur2 = (float*)d_out;                            // [T,B,1] flat
    float* out_spk  = (float*)d_out + (size_t)T_STEPS * BATCH;  // [T,B,200] flat

    rsnn_kernel<<<BATCH, 256, 0, stream>>>(X, W1, b1, Wrec, brec, out_spk);
    cur2_kernel<<<1024, 256, 0, stream>>>(out_spk, W2, b2, out_cur2);
}

// Round 24
// 538.023 us; speedup vs baseline: 1.2948x; 1.0290x over previous
//
#include <hip/hip_runtime.h>

#define T_STEPS 1000
#define BATCH   256
#define NHID    200
#define ROWF    200      // floats per LDS row (800 B, 16B-aligned)
#define BETA_C  0.85f
#define THR_C   1.0f

// WT2 row i (source neuron i) holds at float offset lo*4+k (lo<50,k<4):
// Wrec[(lo+50k)][i]. Lane lo reads ONE ds_read_b128 per firing source i,
// yielding weights for outputs {lo, lo+50, lo+100, lo+150}.
//
// R19 structure (507 us, re-validation-stable): 4 waves per batch element;
// wave w gathers source word w and owns output word w; TWO-barrier
// fixed-layout exchange; inputs batched 8 steps/group into registers.
// NEW (single variable): dual-group gather with ZERO-INIT fallbacks.
// R20's version seeded v4..v7 from v0 -> data dependency forced the
// group-1 wait before group-2 issue (re-serialized; why it was neutral).
// Zeros carry no dependency (group-2 values only consumed inside if(s8)),
// and sched_barrier(0) at the join keeps the group-1 accumulate from being
// hoisted above the group-2 issue. Adds identical, ascending -> bit-exact.
// cur2 recomputed by a second kernel from stored spikes.

#define BARRIER_LGKM \
    asm volatile("s_waitcnt lgkmcnt(0)\n\ts_barrier" ::: "memory");

__launch_bounds__(256, 1)
__global__ void rsnn_kernel(const float* __restrict__ X,
                            const float* __restrict__ W1,
                            const float* __restrict__ b1,
                            const float* __restrict__ Wrec,
                            const float* __restrict__ brec,
                            float* __restrict__ out_spk) {
#pragma clang fp contract(off)
    __shared__ float WT2[NHID * ROWF];   // 160,000 B
    __shared__ float part[4][4][50];     //   3,200 B  [comp][src wave][lane]

    const int tid = threadIdx.x;
    const int l   = tid & 63;            // lane
    const int w   = tid >> 6;            // wave id = source & output word id
    const int b   = blockIdx.x;

    // ---- stage Wrec (permuted transpose) into LDS ----
    for (int idx = tid; idx < NHID * NHID; idx += 256) {
        int r  = idx / NHID;             // Wrec row  (output neuron)
        int i  = idx - r * NHID;         // Wrec col  (source neuron)
        int lo = r % 50, k = r / 50;
        WT2[i * ROWF + lo * 4 + k] = Wrec[idx];
    }
    __syncthreads();

    const int lc = (l < 50) ? l : 49;    // lanes 50-63 duplicate lane 49
    const int oc = 50 * w + lc;          // this lane's output neuron
    const float w10 = W1[oc * 3 + 0], w11 = W1[oc * 3 + 1], w12 = W1[oc * 3 + 2];
    const float b1j = b1[oc], brj = brec[oc];

    float mem = 0.f;
    unsigned long long bm = 0;           // own word's spike mask

    const float* xp = X + (size_t)b * 3;

    const float* ldsrow  = WT2 + (size_t)lc * 4;
    const int    wbase   = 50 * w;
    float*       spk_out = out_spk + (size_t)b * NHID + wbase + lc;

    // ---- current 8-step group of inputs, fully in registers ----
    float xc[8][3];
#pragma unroll
    for (int k = 0; k < 8; ++k) {
        xc[k][0] = xp[(size_t)k * (BATCH * 3) + 0];
        xc[k][1] = xp[(size_t)k * (BATCH * 3) + 1];
        xc[k][2] = xp[(size_t)k * (BATCH * 3) + 2];
    }

// Dual-group gather trip: extract+issue 4, then (wave-uniform branch)
// extract+issue 4 more, sched_barrier(0), acc group 1 (counted wait
// lgkmcnt(4)), acc group 2. Fallbacks are ZEROS (no dependency on group-1
// loads). Same adds in same ascending order as R19 -> bit-exact.
#define REC_WORD(MASK, BASE)                                                          \
    {                                                                                 \
        unsigned long long m = (MASK);                                                \
        while (m) {                                                                   \
            int i0 = __builtin_ctzll(m); m &= m - 1;                                  \
            bool h1 = m != 0; int i1 = h1 ? __builtin_ctzll(m) : i0; if (h1) m &= m - 1; \
            bool h2 = m != 0; int i2 = h2 ? __builtin_ctzll(m) : i0; if (h2) m &= m - 1; \
            bool h3 = m != 0; int i3 = h3 ? __builtin_ctzll(m) : i0; if (h3) m &= m - 1; \
            const float4 v0 = *(const float4*)(ldsrow + (i0 + (BASE)) * ROWF);        \
            const float4 v1 = *(const float4*)(ldsrow + (i1 + (BASE)) * ROWF);        \
            const float4 v2 = *(const float4*)(ldsrow + (i2 + (BASE)) * ROWF);        \
            const float4 v3 = *(const float4*)(ldsrow + (i3 + (BASE)) * ROWF);        \
            bool s8 = m != 0;                                                         \
            bool h5 = false, h6 = false, h7 = false;                                  \
            float4 v4 = {0.f, 0.f, 0.f, 0.f};                                         \
            float4 v5 = v4, v6 = v4, v7 = v4;                                         \
            if (s8) {                                                                 \
                int i4 = __builtin_ctzll(m); m &= m - 1;                              \
                h5 = m != 0; int i5 = h5 ? __builtin_ctzll(m) : i4; if (h5) m &= m - 1; \
                h6 = m != 0; int i6 = h6 ? __builtin_ctzll(m) : i4; if (h6) m &= m - 1; \
                h7 = m != 0; int i7 = h7 ? __builtin_ctzll(m) : i4; if (h7) m &= m - 1; \
                v4 = *(const float4*)(ldsrow + (i4 + (BASE)) * ROWF);                 \
                v5 = *(const float4*)(ldsrow + (i5 + (BASE)) * ROWF);                 \
                v6 = *(const float4*)(ldsrow + (i6 + (BASE)) * ROWF);                 \
                v7 = *(const float4*)(ldsrow + (i7 + (BASE)) * ROWF);                 \
            }                                                                         \
            __builtin_amdgcn_sched_barrier(0);                                        \
            pr0 += v0.x; pr1 += v0.y; pr2 += v0.z; pr3 += v0.w;                       \
            if (h1) { pr0 += v1.x; pr1 += v1.y; pr2 += v1.z; pr3 += v1.w; }           \
            if (h2) { pr0 += v2.x; pr1 += v2.y; pr2 += v2.z; pr3 += v2.w; }           \
            if (h3) { pr0 += v3.x; pr1 += v3.y; pr2 += v3.z; pr3 += v3.w; }           \
            if (s8) {                                                                 \
                pr0 += v4.x; pr1 += v4.y; pr2 += v4.z; pr3 += v4.w;                   \
                if (h5) { pr0 += v5.x; pr1 += v5.y; pr2 += v5.z; pr3 += v5.w; }       \
                if (h6) { pr0 += v6.x; pr1 += v6.y; pr2 += v6.z; pr3 += v6.w; }       \
                if (h7) { pr0 += v7.x; pr1 += v7.y; pr2 += v7.z; pr3 += v7.w; }       \
            }                                                                         \
        }                                                                             \
    }

// One time step (R19 two-barrier body; x from registers).
#define STEP(T, K)                                                       \
    {                                                                    \
        const int t = (T);                                               \
                                                                         \
        float pr0 = 0.f, pr1 = 0.f, pr2 = 0.f, pr3 = 0.f;                \
        REC_WORD(bm, wbase)                                              \
                                                                         \
        if (l < 50) {                                                    \
            part[0][w][l] = pr0;                                         \
            part[1][w][l] = pr1;                                         \
            part[2][w][l] = pr2;                                         \
            part[3][w][l] = pr3;                                         \
        }                                                                \
        BARRIER_LGKM                                                     \
                                                                         \
        float p0 = part[w][0][lc], p1 = part[w][1][lc];                  \
        float p2 = part[w][2][lc], p3 = part[w][3][lc];                  \
        float rec = ((p0 + p1) + p2) + p3;                               \
        BARRIER_LGKM                                                     \
                                                                         \
        float c1 = fmaf(xc[K][2], w12,                                   \
                        fmaf(xc[K][1], w11, xc[K][0] * w10)) + b1j;      \
        float ba = ((BETA_C * mem + c1) + rec) + brj;                    \
        float nm = (mem > THR_C) ? 0.f : ba;                             \
        float sp = (nm > THR_C) ? 1.f : 0.f;                             \
        mem = nm;                                                        \
                                                                         \
        if (l < 50)                                                      \
            spk_out[(size_t)t * BATCH * NHID] = sp;                      \
        bm = __ballot((l < 50) && (sp > 0.5f));                          \
    }

    for (int g = 0; g < T_STEPS; g += 8) {
        // issue next group's 24 input loads; their SMEM latency is drained
        // once (first barrier of step g), steps g+1..g+7 are SMEM-free
        const int gn = (g + 8 < T_STEPS) ? g + 8 : 0;   // last group: dummy
        float xn[8][3];
#pragma unroll
        for (int k = 0; k < 8; ++k) {
            xn[k][0] = xp[(size_t)(gn + k) * (BATCH * 3) + 0];
            xn[k][1] = xp[(size_t)(gn + k) * (BATCH * 3) + 1];
            xn[k][2] = xp[(size_t)(gn + k) * (BATCH * 3) + 2];
        }

        STEP(g + 0, 0)
        STEP(g + 1, 1)
        STEP(g + 2, 2)
        STEP(g + 3, 3)
        STEP(g + 4, 4)
        STEP(g + 5, 5)
        STEP(g + 6, 6)
        STEP(g + 7, 7)

#pragma unroll
        for (int k = 0; k < 8; ++k) {
            xc[k][0] = xn[k][0];
            xc[k][1] = xn[k][1];
            xc[k][2] = xn[k][2];
        }
    }
#undef STEP
#undef REC_WORD
}

// cur2[t,b] = sum_j spk[t,b,j]*W2[j] + b2 — recomputed from stored spikes
// (L3-resident). Terminal output: tree reduction order is safe.
__launch_bounds__(256)
__global__ void cur2_kernel(const float* __restrict__ spk,
                            const float* __restrict__ W2,
                            const float* __restrict__ b2,
                            float* __restrict__ out) {
    const int lane = threadIdx.x & 63;
    const int wid  = (int)((blockIdx.x * blockDim.x + threadIdx.x) >> 6);
    const int nw   = (int)((gridDim.x * blockDim.x) >> 6);

    float4 w2v = {0.f, 0.f, 0.f, 0.f};
    if (lane < 50) w2v = *(const float4*)(W2 + lane * 4);
    const float b2v = b2[0];

    for (int p = wid; p < T_STEPS * BATCH; p += nw) {
        float4 sv = {0.f, 0.f, 0.f, 0.f};
        if (lane < 50) sv = *(const float4*)(spk + (size_t)p * NHID + lane * 4);
        float a = fmaf(sv.w, w2v.w, fmaf(sv.z, w2v.z,
                  fmaf(sv.y, w2v.y, sv.x * w2v.x)));
#pragma unroll
        for (int o = 32; o >= 1; o >>= 1) a += __shfl_xor(a, o);
        if (lane == 0) out[p] = a + b2v;   // p = t*BATCH + b
    }
}

extern "C" void kernel_launch(void* const* d_in, const int* in_sizes, int n_in,
                              void* d_out, int out_size, void* d_ws, size_t ws_size,
                              hipStream_t stream) {
    const float* X    = (const float*)d_in[0];
    const float* W1   = (const float*)d_in[1];
    const float* b1   = (const float*)d_in[2];
    const float* Wrec = (const float*)d_in[3];
    const float* brec = (const float*)d_in[4];
    const float* W2   = (const float*)d_in[5];
    const float* b2   = (const float*)d_in[6];

    float* out_cur2 = (float*)d_out;                            // [T,B,1] flat
    float* out_spk  = (float*)d_out + (size_t)T_STEPS * BATCH;  // [T,B,200] flat

    rsnn_kernel<<<BATCH, 256, 0, stream>>>(X, W1, b1, Wrec, brec, out_spk);
    cur2_kernel<<<1024, 256, 0, stream>>>(out_spk, W2, b2, out_cur2);
}

// Round 25
// 511.639 us; speedup vs baseline: 1.3615x; 1.0516x over previous
//
#include <hip/hip_runtime.h>

#define T_STEPS 1000
#define BATCH   256
#define NHID    200
#define ROWF    200      // floats per LDS row (800 B, 16B-aligned)
#define BETA_C  0.85f
#define THR_C   1.0f

// WT2 row i (source neuron i) holds at float offset lo*4+k (lo<50,k<4):
// Wrec[(lo+50k)][i]. Lane lo reads ONE ds_read_b128 per firing source i,
// yielding weights for outputs {lo, lo+50, lo+100, lo+150}.
//
// R19 structure (507 us, re-validation-stable): 4 waves per batch element;
// wave w gathers source word w and owns output word w; TWO-barrier
// fixed-layout exchange; inputs batched 8 steps/group into registers.
// NEW (single variable): branch-duplicated dual-group gather. Group-1's 4
// loads issue, then a wave-uniform if(m) whose taken path issues group-2's
// 4 loads AND does both accumulates (else path: group-1 accumulates only).
// No fallback values -> no v_movs (R24's regression), no sched fence; the
// compiler emits issue(4) / issue(4) / lgkmcnt(4) / acc / lgkmcnt(0) / acc,
// halving exposed LDS waits on words with >=5 firing. Adds are identical
// ops in identical ascending order in both paths -> bit-exact.
// cur2 recomputed by a second kernel from stored spikes.

#define BARRIER_LGKM \
    asm volatile("s_waitcnt lgkmcnt(0)\n\ts_barrier" ::: "memory");

__launch_bounds__(256, 1)
__global__ void rsnn_kernel(const float* __restrict__ X,
                            const float* __restrict__ W1,
                            const float* __restrict__ b1,
                            const float* __restrict__ Wrec,
                            const float* __restrict__ brec,
                            float* __restrict__ out_spk) {
#pragma clang fp contract(off)
    __shared__ float WT2[NHID * ROWF];   // 160,000 B
    __shared__ float part[4][4][50];     //   3,200 B  [comp][src wave][lane]

    const int tid = threadIdx.x;
    const int l   = tid & 63;            // lane
    const int w   = tid >> 6;            // wave id = source & output word id
    const int b   = blockIdx.x;

    // ---- stage Wrec (permuted transpose) into LDS ----
    for (int idx = tid; idx < NHID * NHID; idx += 256) {
        int r  = idx / NHID;             // Wrec row  (output neuron)
        int i  = idx - r * NHID;         // Wrec col  (source neuron)
        int lo = r % 50, k = r / 50;
        WT2[i * ROWF + lo * 4 + k] = Wrec[idx];
    }
    __syncthreads();

    const int lc = (l < 50) ? l : 49;    // lanes 50-63 duplicate lane 49
    const int oc = 50 * w + lc;          // this lane's output neuron
    const float w10 = W1[oc * 3 + 0], w11 = W1[oc * 3 + 1], w12 = W1[oc * 3 + 2];
    const float b1j = b1[oc], brj = brec[oc];

    float mem = 0.f;
    unsigned long long bm = 0;           // own word's spike mask

    const float* xp = X + (size_t)b * 3;

    const float* ldsrow  = WT2 + (size_t)lc * 4;
    const int    wbase   = 50 * w;
    float*       spk_out = out_spk + (size_t)b * NHID + wbase + lc;

    // ---- current 8-step group of inputs, fully in registers ----
    float xc[8][3];
#pragma unroll
    for (int k = 0; k < 8; ++k) {
        xc[k][0] = xp[(size_t)k * (BATCH * 3) + 0];
        xc[k][1] = xp[(size_t)k * (BATCH * 3) + 1];
        xc[k][2] = xp[(size_t)k * (BATCH * 3) + 2];
    }

#define ACC4(VA, VB, VC, VD)                                           \
    pr0 += VA.x; pr1 += VA.y; pr2 += VA.z; pr3 += VA.w;                \
    if (h1) { pr0 += VB.x; pr1 += VB.y; pr2 += VB.z; pr3 += VB.w; }    \
    if (h2) { pr0 += VC.x; pr1 += VC.y; pr2 += VC.z; pr3 += VC.w; }    \
    if (h3) { pr0 += VD.x; pr1 += VD.y; pr2 += VD.z; pr3 += VD.w; }

// Branch-duplicated dual-group trip (see header comment).
#define REC_WORD(MASK, BASE)                                                          \
    {                                                                                 \
        unsigned long long m = (MASK);                                                \
        while (m) {                                                                   \
            int i0 = __builtin_ctzll(m); m &= m - 1;                                  \
            bool h1 = m != 0; int i1 = h1 ? __builtin_ctzll(m) : i0; if (h1) m &= m - 1; \
            bool h2 = m != 0; int i2 = h2 ? __builtin_ctzll(m) : i0; if (h2) m &= m - 1; \
            bool h3 = m != 0; int i3 = h3 ? __builtin_ctzll(m) : i0; if (h3) m &= m - 1; \
            const float4 v0 = *(const float4*)(ldsrow + (i0 + (BASE)) * ROWF);        \
            const float4 v1 = *(const float4*)(ldsrow + (i1 + (BASE)) * ROWF);        \
            const float4 v2 = *(const float4*)(ldsrow + (i2 + (BASE)) * ROWF);        \
            const float4 v3 = *(const float4*)(ldsrow + (i3 + (BASE)) * ROWF);        \
            if (m) {                                                                  \
                int i4 = __builtin_ctzll(m); m &= m - 1;                              \
                bool h5 = m != 0; int i5 = h5 ? __builtin_ctzll(m) : i4; if (h5) m &= m - 1; \
                bool h6 = m != 0; int i6 = h6 ? __builtin_ctzll(m) : i4; if (h6) m &= m - 1; \
                bool h7 = m != 0; int i7 = h7 ? __builtin_ctzll(m) : i4; if (h7) m &= m - 1; \
                const float4 v4 = *(const float4*)(ldsrow + (i4 + (BASE)) * ROWF);    \
                const float4 v5 = *(const float4*)(ldsrow + (i5 + (BASE)) * ROWF);    \
                const float4 v6 = *(const float4*)(ldsrow + (i6 + (BASE)) * ROWF);    \
                const float4 v7 = *(const float4*)(ldsrow + (i7 + (BASE)) * ROWF);    \
                ACC4(v0, v1, v2, v3)                                                  \
                pr0 += v4.x; pr1 += v4.y; pr2 += v4.z; pr3 += v4.w;                   \
                if (h5) { pr0 += v5.x; pr1 += v5.y; pr2 += v5.z; pr3 += v5.w; }       \
                if (h6) { pr0 += v6.x; pr1 += v6.y; pr2 += v6.z; pr3 += v6.w; }       \
                if (h7) { pr0 += v7.x; pr1 += v7.y; pr2 += v7.z; pr3 += v7.w; }       \
            } else {                                                                  \
                ACC4(v0, v1, v2, v3)                                                  \
            }                                                                         \
        }                                                                             \
    }

// One time step (R19 two-barrier body; x from registers).
#define STEP(T, K)                                                       \
    {                                                                    \
        const int t = (T);                                               \
                                                                         \
        float pr0 = 0.f, pr1 = 0.f, pr2 = 0.f, pr3 = 0.f;                \
        REC_WORD(bm, wbase)                                              \
                                                                         \
        if (l < 50) {                                                    \
            part[0][w][l] = pr0;                                         \
            part[1][w][l] = pr1;                                         \
            part[2][w][l] = pr2;                                         \
            part[3][w][l] = pr3;                                         \
        }                                                                \
        BARRIER_LGKM                                                     \
                                                                         \
        float p0 = part[w][0][lc], p1 = part[w][1][lc];                  \
        float p2 = part[w][2][lc], p3 = part[w][3][lc];                  \
        float rec = ((p0 + p1) + p2) + p3;                               \
        BARRIER_LGKM                                                     \
                                                                         \
        float c1 = fmaf(xc[K][2], w12,                                   \
                        fmaf(xc[K][1], w11, xc[K][0] * w10)) + b1j;      \
        float ba = ((BETA_C * mem + c1) + rec) + brj;                    \
        float nm = (mem > THR_C) ? 0.f : ba;                             \
        float sp = (nm > THR_C) ? 1.f : 0.f;                             \
        mem = nm;                                                        \
                                                                         \
        if (l < 50)                                                      \
            spk_out[(size_t)t * BATCH * NHID] = sp;                      \
        bm = __ballot((l < 50) && (sp > 0.5f));                          \
    }

    for (int g = 0; g < T_STEPS; g += 8) {
        // issue next group's 24 input loads; their SMEM latency is drained
        // once (first barrier of step g), steps g+1..g+7 are SMEM-free
        const int gn = (g + 8 < T_STEPS) ? g + 8 : 0;   // last group: dummy
        float xn[8][3];
#pragma unroll
        for (int k = 0; k < 8; ++k) {
            xn[k][0] = xp[(size_t)(gn + k) * (BATCH * 3) + 0];
            xn[k][1] = xp[(size_t)(gn + k) * (BATCH * 3) + 1];
            xn[k][2] = xp[(size_t)(gn + k) * (BATCH * 3) + 2];
        }

        STEP(g + 0, 0)
        STEP(g + 1, 1)
        STEP(g + 2, 2)
        STEP(g + 3, 3)
        STEP(g + 4, 4)
        STEP(g + 5, 5)
        STEP(g + 6, 6)
        STEP(g + 7, 7)

#pragma unroll
        for (int k = 0; k < 8; ++k) {
            xc[k][0] = xn[k][0];
            xc[k][1] = xn[k][1];
            xc[k][2] = xn[k][2];
        }
    }
#undef STEP
#undef REC_WORD
#undef ACC4
}

// cur2[t,b] = sum_j spk[t,b,j]*W2[j] + b2 — recomputed from stored spikes
// (L3-resident). Terminal output: tree reduction order is safe.
__launch_bounds__(256)
__global__ void cur2_kernel(const float* __restrict__ spk,
                            const float* __restrict__ W2,
                            const float* __restrict__ b2,
                            float* __restrict__ out) {
    const int lane = threadIdx.x & 63;
    const int wid  = (int)((blockIdx.x * blockDim.x + threadIdx.x) >> 6);
    const int nw   = (int)((gridDim.x * blockDim.x) >> 6);

    float4 w2v = {0.f, 0.f, 0.f, 0.f};
    if (lane < 50) w2v = *(const float4*)(W2 + lane * 4);
    const float b2v = b2[0];

    for (int p = wid; p < T_STEPS * BATCH; p += nw) {
        float4 sv = {0.f, 0.f, 0.f, 0.f};
        if (lane < 50) sv = *(const float4*)(spk + (size_t)p * NHID + lane * 4);
        float a = fmaf(sv.w, w2v.w, fmaf(sv.z, w2v.z,
                  fmaf(sv.y, w2v.y, sv.x * w2v.x)));
#pragma unroll
        for (int o = 32; o >= 1; o >>= 1) a += __shfl_xor(a, o);
        if (lane == 0) out[p] = a + b2v;   // p = t*BATCH + b
    }
}

extern "C" void kernel_launch(void* const* d_in, const int* in_sizes, int n_in,
                              void* d_out, int out_size, void* d_ws, size_t ws_size,
                              hipStream_t stream) {
    const float* X    = (const float*)d_in[0];
    const float* W1   = (const float*)d_in[1];
    const float* b1   = (const float*)d_in[2];
    const float* Wrec = (const float*)d_in[3];
    const float* brec = (const float*)d_in[4];
    const float* W2   = (const float*)d_in[5];
    const float* b2   = (const float*)d_in[6];

    float* out_cur2 = (float*)d_out;                            // [T,B,1] flat
    float* out_spk  = (float*)d_out + (size_t)T_STEPS * BATCH;  // [T,B,200] flat

    rsnn_kernel<<<BATCH, 256, 0, stream>>>(X, W1, b1, Wrec, brec, out_spk);
    cur2_kernel<<<1024, 256, 0, stream>>>(out_spk, W2, b2, out_cur2);
}

// Round 26
// 511.198 us; speedup vs baseline: 1.3627x; 1.0009x over previous
//
#include <hip/hip_runtime.h>

#define T_STEPS 1000
#define BATCH   256
#define NHID    200
#define ROWF    200      // floats per LDS row (800 B, 16B-aligned)
#define BETA_C  0.85f
#define THR_C   1.0f

// FINAL (R19 structure, best stable: ~507 us).
// WT2 row i (source neuron i) holds at float offset lo*4+k (lo<50,k<4):
// Wrec[(lo+50k)][i]. Lane lo reads ONE ds_read_b128 per firing source i,
// yielding weights for outputs {lo, lo+50, lo+100, lo+150}.
//
// 4 waves per batch element; wave w gathers source word w (~7 firing,
// 4-wide ascending trips) and owns output word w. TWO-barrier fixed-layout
// partial exchange (validated under graph replay): write part[c][w] -> BAR
// -> read part[w][s] + reduce ((p0+p1)+p2)+p3 -> BAR -> update. Inputs
// batched 8 steps/group into registers (SMEM shares lgkmcnt with DS; the
// ~200-cyc scalar-load drain is paid once per 8 steps, not every step —
// worth ~95 us). Barriers are raw s_barrier with lgkmcnt-only drain so the
// fire-and-forget global spike stores are never drained on the critical
// path. cur2 recomputed by a second kernel from the stored spikes
// (terminal output; removes the shfl-tree from the recurrent chain).
//
// Converged-floor note: per-step serial chain ~1174 cyc = mask-dependent
// LDS gather (un-pipelineable at source level; R3-R9, R16/17/20/24/25 all
// neutral-or-worse) + cross-wave exchange (2 barriers optimal; R15/21/23
// single-barrier variants slower or flaky) + update/ballot. No throughput
// resource is near saturation (HBM ~6%, VALU ~15%) — latency-bound.

#define BARRIER_LGKM \
    asm volatile("s_waitcnt lgkmcnt(0)\n\ts_barrier" ::: "memory");

__launch_bounds__(256, 1)
__global__ void rsnn_kernel(const float* __restrict__ X,
                            const float* __restrict__ W1,
                            const float* __restrict__ b1,
                            const float* __restrict__ Wrec,
                            const float* __restrict__ brec,
                            float* __restrict__ out_spk) {
#pragma clang fp contract(off)
    __shared__ float WT2[NHID * ROWF];   // 160,000 B
    __shared__ float part[4][4][50];     //   3,200 B  [comp][src wave][lane]

    const int tid = threadIdx.x;
    const int l   = tid & 63;            // lane
    const int w   = tid >> 6;            // wave id = source & output word id
    const int b   = blockIdx.x;

    // ---- stage Wrec (permuted transpose) into LDS ----
    for (int idx = tid; idx < NHID * NHID; idx += 256) {
        int r  = idx / NHID;             // Wrec row  (output neuron)
        int i  = idx - r * NHID;         // Wrec col  (source neuron)
        int lo = r % 50, k = r / 50;
        WT2[i * ROWF + lo * 4 + k] = Wrec[idx];
    }
    __syncthreads();

    const int lc = (l < 50) ? l : 49;    // lanes 50-63 duplicate lane 49
    const int oc = 50 * w + lc;          // this lane's output neuron
    const float w10 = W1[oc * 3 + 0], w11 = W1[oc * 3 + 1], w12 = W1[oc * 3 + 2];
    const float b1j = b1[oc], brj = brec[oc];

    float mem = 0.f;
    unsigned long long bm = 0;           // own word's spike mask

    const float* xp = X + (size_t)b * 3;

    const float* ldsrow  = WT2 + (size_t)lc * 4;
    const int    wbase   = 50 * w;
    float*       spk_out = out_spk + (size_t)b * NHID + wbase + lc;

    // ---- current 8-step group of inputs, fully in registers ----
    float xc[8][3];
#pragma unroll
    for (int k = 0; k < 8; ++k) {
        xc[k][0] = xp[(size_t)k * (BATCH * 3) + 0];
        xc[k][1] = xp[(size_t)k * (BATCH * 3) + 1];
        xc[k][2] = xp[(size_t)k * (BATCH * 3) + 2];
    }

#define REC_WORD(MASK, BASE)                                                          \
    {                                                                                 \
        unsigned long long m = (MASK);                                                \
        while (m) {                                                                   \
            int i0 = __builtin_ctzll(m); m &= m - 1;                                  \
            bool h1 = m != 0; int i1 = h1 ? __builtin_ctzll(m) : i0; if (h1) m &= m - 1; \
            bool h2 = m != 0; int i2 = h2 ? __builtin_ctzll(m) : i0; if (h2) m &= m - 1; \
            bool h3 = m != 0; int i3 = h3 ? __builtin_ctzll(m) : i0; if (h3) m &= m - 1; \
            const float4 v0 = *(const float4*)(ldsrow + (i0 + (BASE)) * ROWF);        \
            const float4 v1 = *(const float4*)(ldsrow + (i1 + (BASE)) * ROWF);        \
            const float4 v2 = *(const float4*)(ldsrow + (i2 + (BASE)) * ROWF);        \
            const float4 v3 = *(const float4*)(ldsrow + (i3 + (BASE)) * ROWF);        \
            pr0 += v0.x; pr1 += v0.y; pr2 += v0.z; pr3 += v0.w;                       \
            if (h1) { pr0 += v1.x; pr1 += v1.y; pr2 += v1.z; pr3 += v1.w; }           \
            if (h2) { pr0 += v2.x; pr1 += v2.y; pr2 += v2.z; pr3 += v2.w; }           \
            if (h3) { pr0 += v3.x; pr1 += v3.y; pr2 += v3.z; pr3 += v3.w; }           \
        }                                                                             \
    }

// One time step (two-barrier body; x from registers).
#define STEP(T, K)                                                       \
    {                                                                    \
        const int t = (T);                                               \
                                                                         \
        float pr0 = 0.f, pr1 = 0.f, pr2 = 0.f, pr3 = 0.f;                \
        REC_WORD(bm, wbase)                                              \
                                                                         \
        if (l < 50) {                                                    \
            part[0][w][l] = pr0;                                         \
            part[1][w][l] = pr1;                                         \
            part[2][w][l] = pr2;                                         \
            part[3][w][l] = pr3;                                         \
        }                                                                \
        BARRIER_LGKM                                                     \
                                                                         \
        float p0 = part[w][0][lc], p1 = part[w][1][lc];                  \
        float p2 = part[w][2][lc], p3 = part[w][3][lc];                  \
        float rec = ((p0 + p1) + p2) + p3;                               \
        BARRIER_LGKM                                                     \
                                                                         \
        float c1 = fmaf(xc[K][2], w12,                                   \
                        fmaf(xc[K][1], w11, xc[K][0] * w10)) + b1j;      \
        float ba = ((BETA_C * mem + c1) + rec) + brj;                    \
        float nm = (mem > THR_C) ? 0.f : ba;                             \
        float sp = (nm > THR_C) ? 1.f : 0.f;                             \
        mem = nm;                                                        \
                                                                         \
        if (l < 50)                                                      \
            spk_out[(size_t)t * BATCH * NHID] = sp;                      \
        bm = __ballot((l < 50) && (sp > 0.5f));                          \
    }

    for (int g = 0; g < T_STEPS; g += 8) {
        // issue next group's 24 input loads; their SMEM latency is drained
        // once (first barrier of step g), steps g+1..g+7 are SMEM-free
        const int gn = (g + 8 < T_STEPS) ? g + 8 : 0;   // last group: dummy
        float xn[8][3];
#pragma unroll
        for (int k = 0; k < 8; ++k) {
            xn[k][0] = xp[(size_t)(gn + k) * (BATCH * 3) + 0];
            xn[k][1] = xp[(size_t)(gn + k) * (BATCH * 3) + 1];
            xn[k][2] = xp[(size_t)(gn + k) * (BATCH * 3) + 2];
        }

        STEP(g + 0, 0)
        STEP(g + 1, 1)
        STEP(g + 2, 2)
        STEP(g + 3, 3)
        STEP(g + 4, 4)
        STEP(g + 5, 5)
        STEP(g + 6, 6)
        STEP(g + 7, 7)

#pragma unroll
        for (int k = 0; k < 8; ++k) {
            xc[k][0] = xn[k][0];
            xc[k][1] = xn[k][1];
            xc[k][2] = xn[k][2];
        }
    }
#undef STEP
#undef REC_WORD
}

// cur2[t,b] = sum_j spk[t,b,j]*W2[j] + b2 — recomputed from stored spikes
// (L3-resident). Terminal output: tree reduction order is safe.
__launch_bounds__(256)
__global__ void cur2_kernel(const float* __restrict__ spk,
                            const float* __restrict__ W2,
                            const float* __restrict__ b2,
                            float* __restrict__ out) {
    const int lane = threadIdx.x & 63;
    const int wid  = (int)((blockIdx.x * blockDim.x + threadIdx.x) >> 6);
    const int nw   = (int)((gridDim.x * blockDim.x) >> 6);

    float4 w2v = {0.f, 0.f, 0.f, 0.f};
    if (lane < 50) w2v = *(const float4*)(W2 + lane * 4);
    const float b2v = b2[0];

    for (int p = wid; p < T_STEPS * BATCH; p += nw) {
        float4 sv = {0.f, 0.f, 0.f, 0.f};
        if (lane < 50) sv = *(const float4*)(spk + (size_t)p * NHID + lane * 4);
        float a = fmaf(sv.w, w2v.w, fmaf(sv.z, w2v.z,
                  fmaf(sv.y, w2v.y, sv.x * w2v.x)));
#pragma unroll
        for (int o = 32; o >= 1; o >>= 1) a += __shfl_xor(a, o);
        if (lane == 0) out[p] = a + b2v;   // p = t*BATCH + b
    }
}

extern "C" void kernel_launch(void* const* d_in, const int* in_sizes, int n_in,
                              void* d_out, int out_size, void* d_ws, size_t ws_size,
                              hipStream_t stream) {
    const float* X    = (const float*)d_in[0];
    const float* W1   = (const float*)d_in[1];
    const float* b1   = (const float*)d_in[2];
    const float* Wrec = (const float*)d_in[3];
    const float* brec = (const float*)d_in[4];
    const float* W2   = (const float*)d_in[5];
    const float* b2   = (const float*)d_in[6];

    float* out_cur2 = (float*)d_out;                            // [T,B,1] flat
    float* out_spk  = (float*)d_out + (size_t)T_STEPS * BATCH;  // [T,B,200] flat

    rsnn_kernel<<<BATCH, 256, 0, stream>>>(X, W1, b1, Wrec, brec, out_spk);
    cur2_kernel<<<1024, 256, 0, stream>>>(out_spk, W2, b2, out_cur2);
}